// Round 1
// baseline (1695.200 us; speedup 1.0000x reference)
//
#include <hip/hip_runtime.h>
#include <hip/hip_bf16.h>

// TuckERT: pred = BN1( einsum(bd,bde->be, BN0(E[x0]), (R[x1]*T[x3]) @ W) ) @ E^T
// plus reg = norm4 of [lhs_n, rel*t, rel_noT, rhs, w], plus T passthrough.
//
// Sizes: B=2048, DIM=200 (K padded to 224), N_ENT=100000, W is 200x200x200.
// Strategy:
//   U[b, d*200+e] = sum_k rel_t[b,k] * W[k,d,e]   -> MFMA GEMM-BT vs W^T(de,k), bf16
//   h[b,e]        = sum_d lhs_n[b,d] * U[b,d,e]   -> memory-bound kernel
//   pred          = BN1(h) @ E^T                  -> MFMA GEMM-BT vs E(e,k), bf16
// U (164 MB bf16) lives in d_out's pred region and is overwritten by the final GEMM.

#define DIMX 200
#define KP   224
#define BATCH 2048
#define NENT 100000
#define EPS_BN 1e-5f

#define NPAD1 40064    /* 313*128  (Tucker GEMM N) */
#define NPAD2 100096   /* 782*128  (pred GEMM N)   */

typedef __attribute__((ext_vector_type(8))) short bf16x8;
typedef __attribute__((ext_vector_type(4))) float floatx4;

__device__ __forceinline__ unsigned short f2bf(float f) {
  __hip_bfloat16 h = __float2bfloat16(f);
  return *reinterpret_cast<unsigned short*>(&h);
}

__device__ __forceinline__ float blk_sum256(float v, float* sm) {
#pragma unroll
  for (int o = 32; o > 0; o >>= 1) v += __shfl_down(v, o);
  __syncthreads();
  if ((threadIdx.x & 63u) == 0) sm[threadIdx.x >> 6] = v;
  __syncthreads();
  return sm[0] + sm[1] + sm[2] + sm[3];
}

// ---------------------------------------------------------------- gather + rel_t + norm4 partials
__global__ __launch_bounds__(256) void gather_k1(
    const int* __restrict__ x, const float* __restrict__ E, const float* __restrict__ R,
    const float* __restrict__ RnT, const float* __restrict__ T,
    float* __restrict__ lhs, unsigned short* __restrict__ reltbf, float* __restrict__ accum) {
  int i = blockIdx.x * 256 + threadIdx.x;  // over BATCH*KP
  int b = i / KP, d = i - b * KP;
  float p1 = 0.f, p2 = 0.f, p3 = 0.f;
  if (d < DIMX) {
    int i0 = x[b * 4 + 0], i1 = x[b * 4 + 1], i2 = x[b * 4 + 2], i3 = x[b * 4 + 3];
    float lv = E[(size_t)i0 * DIMX + d];
    lhs[b * DIMX + d] = lv;
    float rt = R[i1 * DIMX + d] * T[i3 * DIMX + d];
    reltbf[i] = f2bf(rt);
    float rn = RnT[i1 * DIMX + d];
    float rh = E[(size_t)i2 * DIMX + d];
    float rt2 = rt * rt, rn2 = rn * rn, rh2 = rh * rh;
    p1 = rt2 * rt2; p2 = rn2 * rn2; p3 = rh2 * rh2;
  } else {
    reltbf[i] = 0;
  }
  __shared__ float sm[12];
  float s1 = blk_sum256(p1, sm);
  float s2 = blk_sum256(p2, sm + 4);
  float s3 = blk_sum256(p3, sm + 8);
  if (threadIdx.x == 0) {
    atomicAdd(&accum[1], s1);
    atomicAdd(&accum[2], s2);
    atomicAdd(&accum[3], s3);
  }
}

// ---------------------------------------------------------------- W (k,de) f32 -> W^T (de,k) bf16, + sum w^4
__global__ __launch_bounds__(256) void wt_transpose(
    const float* __restrict__ W, unsigned short* __restrict__ Wt, float* __restrict__ accum) {
  int i = blockIdx.x * 256 + threadIdx.x;  // over NPAD1*KP
  int n = i / KP, k = i - n * KP;
  float p = 0.f;
  unsigned short o = 0;
  if (n < 40000 && k < DIMX) {
    float w = W[(size_t)k * 40000 + n];
    o = f2bf(w);
    float w2 = w * w;
    p = w2 * w2;
  }
  Wt[i] = o;
  __shared__ float sm[4];
  float s = blk_sum256(p, sm);
  if (threadIdx.x == 0) atomicAdd(&accum[4], s);
}

// ---------------------------------------------------------------- E (e,200) f32 -> (e,224) bf16 zero-padded
__global__ __launch_bounds__(256) void ebf_conv(const float* __restrict__ E, unsigned short* __restrict__ Ebf) {
  int i = blockIdx.x * 256 + threadIdx.x;  // over NPAD2*KP
  int e = i / KP, k = i - e * KP;
  unsigned short o = 0;
  if (e < NENT && k < DIMX) o = f2bf(E[(size_t)e * DIMX + k]);
  Ebf[i] = o;
}

// ---------------------------------------------------------------- per-column mean / rstd over batch
__global__ __launch_bounds__(256) void colstats(const float* __restrict__ X, float* __restrict__ mu, float* __restrict__ rs) {
  int c = blockIdx.x;
  float s = 0.f, s2 = 0.f;
  for (int b = threadIdx.x; b < BATCH; b += 256) {
    float v = X[b * DIMX + c];
    s += v; s2 += v * v;
  }
  __shared__ float sm[8];
#pragma unroll
  for (int o = 32; o > 0; o >>= 1) { s += __shfl_down(s, o); s2 += __shfl_down(s2, o); }
  if ((threadIdx.x & 63u) == 0) { sm[threadIdx.x >> 6] = s; sm[4 + (threadIdx.x >> 6)] = s2; }
  __syncthreads();
  if (threadIdx.x == 0) {
    s = sm[0] + sm[1] + sm[2] + sm[3];
    s2 = sm[4] + sm[5] + sm[6] + sm[7];
    float m = s * (1.f / BATCH);
    float var = s2 * (1.f / BATCH) - m * m;
    mu[c] = m;
    rs[c] = rsqrtf(fmaxf(var, 0.f) + EPS_BN);
  }
}

// ---------------------------------------------------------------- BN0 apply (f32 out) + sum lhs_n^4
__global__ __launch_bounds__(256) void apply0(
    const float* __restrict__ lhs, const float* __restrict__ mu, const float* __restrict__ rs,
    const float* __restrict__ g, const float* __restrict__ be,
    float* __restrict__ lhsn, float* __restrict__ accum) {
  int i = blockIdx.x * 256 + threadIdx.x;  // over BATCH*DIMX
  int d = i % DIMX;
  float v = (lhs[i] - mu[d]) * rs[d] * g[d] + be[d];
  lhsn[i] = v;
  float v2 = v * v;
  __shared__ float sm[4];
  float s = blk_sum256(v2 * v2, sm);
  if (threadIdx.x == 0) atomicAdd(&accum[0], s);
}

// ---------------------------------------------------------------- BN1 apply -> bf16 K-padded
__global__ __launch_bounds__(256) void apply1(
    const float* __restrict__ h, const float* __restrict__ mu, const float* __restrict__ rs,
    const float* __restrict__ g, const float* __restrict__ be, unsigned short* __restrict__ hbnbf) {
  int i = blockIdx.x * 256 + threadIdx.x;  // over BATCH*KP
  int b = i / KP, k = i - b * KP;
  unsigned short o = 0;
  if (k < DIMX) {
    float v = (h[b * DIMX + k] - mu[k]) * rs[k] * g[k] + be[k];
    o = f2bf(v);
  }
  hbnbf[i] = o;
}

// ---------------------------------------------------------------- MFMA GEMM: C[m,n] = sum_k A[m,k]*Bt[n,k]
// A: M x KP bf16 (M=2048), Bt: Npad x KP bf16, 128x128 tile, 4 waves of 64x64, 16x16x32 MFMA.
template <bool OUT_BF16>
__global__ __launch_bounds__(256) void gemm_bt(
    const unsigned short* __restrict__ A, const unsigned short* __restrict__ Bt,
    void* __restrict__ Cout, int Nreal) {
  constexpr int LSTR = 40;  // 32 + 8 pad (keeps 16B alignment, breaks bank cycle)
  __shared__ unsigned short As[128 * LSTR];
  __shared__ unsigned short Bs[128 * LSTR];
  const int t = threadIdx.x;
  const int wave = t >> 6, lane = t & 63;
  const int wm = wave >> 1, wn = wave & 1;
  const int m0 = blockIdx.y * 128, n0 = blockIdx.x * 128;
  const int l15 = lane & 15, quad = lane >> 4;

  floatx4 acc[4][4];
#pragma unroll
  for (int i = 0; i < 4; i++)
#pragma unroll
    for (int j = 0; j < 4; j++) acc[i][j] = floatx4{0.f, 0.f, 0.f, 0.f};

  int rowS[2], colS[2];
#pragma unroll
  for (int it = 0; it < 2; ++it) {
    int seg = it * 256 + t;          // 512 x 16B segments per 128x32 tile
    rowS[it] = seg >> 2;
    colS[it] = (seg & 3) * 8;
  }
  bf16x8 ra[2], rb[2];
#pragma unroll
  for (int it = 0; it < 2; ++it) {   // prefetch kk=0
    ra[it] = *(const bf16x8*)(A + (size_t)(m0 + rowS[it]) * KP + colS[it]);
    rb[it] = *(const bf16x8*)(Bt + (size_t)(n0 + rowS[it]) * KP + colS[it]);
  }

  constexpr int KITER = KP / 32;
  for (int kk = 0; kk < KITER; ++kk) {
    __syncthreads();
#pragma unroll
    for (int it = 0; it < 2; ++it) {
      *(bf16x8*)(&As[rowS[it] * LSTR + colS[it]]) = ra[it];
      *(bf16x8*)(&Bs[rowS[it] * LSTR + colS[it]]) = rb[it];
    }
    __syncthreads();
    if (kk + 1 < KITER) {
      int ko = (kk + 1) * 32;
#pragma unroll
      for (int it = 0; it < 2; ++it) {
        ra[it] = *(const bf16x8*)(A + (size_t)(m0 + rowS[it]) * KP + ko + colS[it]);
        rb[it] = *(const bf16x8*)(Bt + (size_t)(n0 + rowS[it]) * KP + ko + colS[it]);
      }
    }
    bf16x8 af[4], bfr[4];
#pragma unroll
    for (int i = 0; i < 4; ++i)
      af[i] = *(const bf16x8*)&As[(wm * 64 + i * 16 + l15) * LSTR + quad * 8];
#pragma unroll
    for (int j = 0; j < 4; ++j)
      bfr[j] = *(const bf16x8*)&Bs[(wn * 64 + j * 16 + l15) * LSTR + quad * 8];
#pragma unroll
    for (int i = 0; i < 4; ++i)
#pragma unroll
      for (int j = 0; j < 4; ++j)
        acc[i][j] = __builtin_amdgcn_mfma_f32_16x16x32_bf16(af[i], bfr[j], acc[i][j], 0, 0, 0);
  }

#pragma unroll
  for (int i = 0; i < 4; ++i) {
    int row = m0 + wm * 64 + i * 16 + quad * 4;  // C/D: col=lane&15, row=quad*4+reg
#pragma unroll
    for (int j = 0; j < 4; ++j) {
      int col = n0 + wn * 64 + j * 16 + l15;
      if (col < Nreal) {
#pragma unroll
        for (int r = 0; r < 4; ++r) {
          size_t off = (size_t)(row + r) * (size_t)Nreal + col;
          if (OUT_BF16) ((unsigned short*)Cout)[off] = f2bf(acc[i][j][r]);
          else ((float*)Cout)[off] = acc[i][j][r];
        }
      }
    }
  }
}

// ---------------------------------------------------------------- h[b,e] = sum_d lhsn[b,d] * U_bf16[b, d*200+e]
__global__ __launch_bounds__(128) void hstep(
    const unsigned short* __restrict__ U, const float* __restrict__ lhsn, float* __restrict__ h) {
  int b = blockIdx.x, t = threadIdx.x;
  __shared__ float sl[DIMX];
  for (int i = t; i < DIMX; i += 128) sl[i] = lhsn[b * DIMX + i];
  __syncthreads();
  if (t < 100) {
    const unsigned short* Ur = U + (size_t)b * 40000;
    float a0 = 0.f, a1 = 0.f;
    for (int d = 0; d < DIMX; ++d) {
      unsigned int u = *(const unsigned int*)(Ur + d * DIMX + 2 * t);
      float w = sl[d];
      a0 += w * __uint_as_float(u << 16);
      a1 += w * __uint_as_float(u & 0xffff0000u);
    }
    h[b * DIMX + 2 * t] = a0;
    h[b * DIMX + 2 * t + 1] = a1;
  }
}

// ---------------------------------------------------------------- tails
__global__ void finalize_reg(const float* __restrict__ accum, float* __restrict__ out) {
  int t = threadIdx.x;
  if (t < 5) out[(size_t)204800000 + t] = sqrtf(sqrtf(accum[t]));
}
__global__ __launch_bounds__(256) void tcopy(const float* __restrict__ T, float* __restrict__ out) {
  int i = blockIdx.x * 256 + threadIdx.x;
  if (i < 400 * DIMX) out[(size_t)204800005 + i] = T[i];
}

extern "C" void kernel_launch(void* const* d_in, const int* in_sizes, int n_in,
                              void* d_out, int out_size, void* d_ws, size_t ws_size,
                              hipStream_t stream) {
  const int* x = (const int*)d_in[0];
  const float* E = (const float*)d_in[1];
  const float* R = (const float*)d_in[2];
  const float* RnT = (const float*)d_in[3];
  const float* T = (const float*)d_in[4];
  const float* W = (const float*)d_in[5];
  const float* g0 = (const float*)d_in[6];
  const float* b0 = (const float*)d_in[7];
  const float* g1 = (const float*)d_in[8];
  const float* b1 = (const float*)d_in[9];

  char* ws = (char*)d_ws;
  float* accum = (float*)ws;                                   // 8 floats (zeroed)
  float* stats = (float*)(ws + 256);                           // mu0,rs0,mu1,rs1 (4*200)
  float* lhs   = (float*)(ws + 4096);                          // 2048*200 f32
  float* lhsn  = (float*)(ws + 4096 + 1638400);                // 2048*200 f32
  float* h     = (float*)(ws + 4096 + 2 * 1638400);            // 2048*200 f32
  unsigned short* reltbf = (unsigned short*)(ws + 4919296);    // 2048*224 bf16
  unsigned short* hbnbf  = (unsigned short*)(ws + 5836800);    // 2048*224 bf16
  unsigned short* Wt     = (unsigned short*)(ws + 6754304);    // 40064*224 bf16
  unsigned short* Ebf    = (unsigned short*)(ws + 24702976);   // 100096*224 bf16  (ends ~66.3MB)

  unsigned short* U = (unsigned short*)d_out;  // 2048*40000 bf16 scratch inside pred region
  float* out = (float*)d_out;

  hipMemsetAsync(accum, 0, 256, stream);
  gather_k1<<<1792, 256, 0, stream>>>(x, E, R, RnT, T, lhs, reltbf, accum);
  wt_transpose<<<35056, 256, 0, stream>>>(W, Wt, accum);
  ebf_conv<<<87584, 256, 0, stream>>>(E, Ebf);
  colstats<<<200, 256, 0, stream>>>(lhs, stats + 0, stats + 200);
  apply0<<<1600, 256, 0, stream>>>(lhs, stats + 0, stats + 200, g0, b0, lhsn, accum);
  gemm_bt<true><<<dim3(313, 16), 256, 0, stream>>>(reltbf, Wt, (void*)U, 40000);
  hstep<<<2048, 128, 0, stream>>>(U, lhsn, h);
  colstats<<<200, 256, 0, stream>>>(h, stats + 400, stats + 600);
  apply1<<<1792, 256, 0, stream>>>(h, stats + 400, stats + 600, g1, b1, hbnbf);
  gemm_bt<false><<<dim3(782, 16), 256, 0, stream>>>(hbnbf, Ebf, d_out, NENT);
  finalize_reg<<<1, 64, 0, stream>>>(accum, out);
  tcopy<<<313, 256, 0, stream>>>(T, out);
}